// Round 1
// baseline (696.641 us; speedup 1.0000x reference)
//
#include <hip/hip_runtime.h>
#include <hip/hip_bf16.h>
#include <math.h>

// ---------------------------------------------------------------------------
// GCN 2-layer: h1 = A_hat @ (x@W1) + b1; relu; h2 = A_hat @ (h1@W2) + b2; log_softmax
// A_hat = D^-1/2 (A + I) D^-1/2.  Strategy:
//   - scale GEMM outputs by dinv[row] in epilogue ("h*s" = h * dinv)
//   - build CSR (by dst) on device each call (histogram/scan/fill, int atomics only)
//   - aggregation: per-node block gathers h*s[src] rows, multiplies by dinv[dst],
//     adds self term h*s[i]*dinv[i], bias, activation. No float atomics.
// ---------------------------------------------------------------------------

#define FEAT1 512
#define FEAT2 128
#define FEAT3 40

// ---- edge_index may be int32 (JAX default) or int64 (if x64 enabled). ------
// Detect: for int64 little-endian nonneg values < 2^31, every odd int32 word
// is 0. For int32 random values in [0,50000) that is astronomically unlikely.
__global__ void detect_i64_kernel(const int* __restrict__ ei, int* flagp) {
    __shared__ int any;
    if (threadIdx.x == 0) any = 0;
    __syncthreads();
    int v = ei[2 * threadIdx.x + 1];   // first 256 odd words
    if (v != 0) any = 1;
    __syncthreads();
    if (threadIdx.x == 0) *flagp = (any == 0) ? 1 : 0;   // 1 => int64 layout
}

__device__ __forceinline__ int load_src(const int* ei, long e, long E, int f64) {
    return f64 ? ei[2 * e] : ei[e];
}
__device__ __forceinline__ int load_dst(const int* ei, long e, long E, int f64) {
    return f64 ? ei[2 * E + 2 * e] : ei[E + e];
}

// ---- CSR build --------------------------------------------------------------
__global__ void hist_kernel(const int* __restrict__ ei, const int* __restrict__ flagp,
                            int* __restrict__ counts, long E) {
    int f64 = *flagp;
    long i = (long)blockIdx.x * blockDim.x + threadIdx.x;
    long stride = (long)gridDim.x * blockDim.x;
    for (; i < E; i += stride) {
        int dst = load_dst(ei, i, E, f64);
        atomicAdd(&counts[dst], 1);
    }
}

// exclusive scan within 256-blocks; bsums gets block total (may be null)
__global__ void scan_block_kernel(const int* __restrict__ in, int* __restrict__ excl,
                                  int* __restrict__ bsums, int N) {
    __shared__ int s[256];
    int t = threadIdx.x;
    int gid = blockIdx.x * 256 + t;
    int v = (gid < N) ? in[gid] : 0;
    s[t] = v;
    __syncthreads();
    #pragma unroll
    for (int d = 1; d < 256; d <<= 1) {
        int tv = (t >= d) ? s[t - d] : 0;
        __syncthreads();
        s[t] += tv;
        __syncthreads();
    }
    if (gid < N) excl[gid] = s[t] - v;
    if (t == 255 && bsums) bsums[blockIdx.x] = s[255];
}

__global__ void scan_finalize_kernel(const int* __restrict__ counts, int* __restrict__ off,
                                     const int* __restrict__ bsums, int* __restrict__ cursor,
                                     float* __restrict__ dinv, int N, int E) {
    int gid = blockIdx.x * 256 + threadIdx.x;
    if (gid < N) {
        int o = off[gid] + bsums[blockIdx.x];
        off[gid] = o;
        cursor[gid] = o;
        dinv[gid] = 1.0f / sqrtf((float)(counts[gid] + 1));  // +1 self-loop; deg>=1
    }
    if (gid == 0) off[N] = E;
}

__global__ void fill_kernel(const int* __restrict__ ei, const int* __restrict__ flagp,
                            int* __restrict__ cursor, int* __restrict__ col, long E) {
    int f64 = *flagp;
    long i = (long)blockIdx.x * blockDim.x + threadIdx.x;
    long stride = (long)gridDim.x * blockDim.x;
    for (; i < E; i += stride) {
        int src = load_src(ei, i, E, f64);
        int dst = load_dst(ei, i, E, f64);
        int pos = atomicAdd(&cursor[dst], 1);
        col[pos] = src;
    }
}

// ---- GEMM1: [M,512] @ [512,128], epilogue * dinv[row] -----------------------
// BM=64 BN=128 BK=32, 256 threads, thread tile 4x8.
__launch_bounds__(256)
__global__ void gemm1_kernel(const float* __restrict__ A, const float* __restrict__ B,
                             const float* __restrict__ dinv, float* __restrict__ C, int M) {
    __shared__ float As[32][64];    // [k][m]
    __shared__ float Bs[32][128];   // [k][n]
    int t = threadIdx.x;
    int m0 = blockIdx.x * 64;
    int ty = t >> 4, tx = t & 15;
    float acc[4][8];
    #pragma unroll
    for (int r = 0; r < 4; r++)
        #pragma unroll
        for (int c = 0; c < 8; c++) acc[r][c] = 0.f;

    for (int k0 = 0; k0 < FEAT1; k0 += 32) {
        #pragma unroll
        for (int i = 0; i < 2; i++) {       // A: 64x32 = 512 float4
            int id = t + i * 256;
            int row = id >> 3;
            int kq = id & 7;
            int grow = m0 + row;
            float4 v = make_float4(0.f, 0.f, 0.f, 0.f);
            if (grow < M) v = *(const float4*)(A + (long)grow * FEAT1 + k0 + kq * 4);
            As[kq * 4 + 0][row] = v.x;
            As[kq * 4 + 1][row] = v.y;
            As[kq * 4 + 2][row] = v.z;
            As[kq * 4 + 3][row] = v.w;
        }
        #pragma unroll
        for (int i = 0; i < 4; i++) {       // B: 32x128 = 1024 float4
            int id = t + i * 256;
            int kr = id >> 5;
            int nq = id & 31;
            *(float4*)(&Bs[kr][nq * 4]) = *(const float4*)(B + (long)(k0 + kr) * FEAT2 + nq * 4);
        }
        __syncthreads();
        #pragma unroll
        for (int kk = 0; kk < 32; ++kk) {
            float ra[4], rb[8];
            #pragma unroll
            for (int r = 0; r < 4; r++) ra[r] = As[kk][ty * 4 + r];
            #pragma unroll
            for (int c = 0; c < 8; c++) rb[c] = Bs[kk][tx * 8 + c];
            #pragma unroll
            for (int r = 0; r < 4; r++)
                #pragma unroll
                for (int c = 0; c < 8; c++) acc[r][c] += ra[r] * rb[c];
        }
        __syncthreads();
    }
    #pragma unroll
    for (int r = 0; r < 4; r++) {
        int grow = m0 + ty * 4 + r;
        if (grow >= M) continue;
        float di = dinv[grow];
        #pragma unroll
        for (int c = 0; c < 8; c += 4) {
            float4 v;
            v.x = acc[r][c + 0] * di;
            v.y = acc[r][c + 1] * di;
            v.z = acc[r][c + 2] * di;
            v.w = acc[r][c + 3] * di;
            *(float4*)(C + (long)grow * FEAT2 + tx * 8 + c) = v;
        }
    }
}

// ---- Aggregation layer 1: block(128) per node, feature f = tid --------------
__launch_bounds__(128)
__global__ void agg1_kernel(const float* __restrict__ h1s, const int* __restrict__ col,
                            const int* __restrict__ off, const float* __restrict__ dinv,
                            const float* __restrict__ b1, float* __restrict__ a1) {
    int i = blockIdx.x;
    int t = threadIdx.x;
    __shared__ int sc[128];
    int o0 = off[i], o1 = off[i + 1];
    float acc = 0.f;
    for (int base = o0; base < o1; base += 128) {
        int cnt = min(128, o1 - base);
        __syncthreads();
        if (t < cnt) sc[t] = col[base + t];
        __syncthreads();
        for (int j = 0; j < cnt; ++j) {
            acc += h1s[(long)sc[j] * FEAT2 + t];
        }
    }
    float di = dinv[i];
    float v = (acc + h1s[(long)i * FEAT2 + t]) * di + b1[t];
    a1[(long)i * FEAT2 + t] = v > 0.f ? v : 0.f;
}

// ---- GEMM2: [M,128] @ [128,40], node-per-thread, epilogue * dinv[row] -------
__launch_bounds__(64)
__global__ void gemm2_kernel(const float* __restrict__ A, const float* __restrict__ W,
                             const float* __restrict__ dinv, float* __restrict__ C, int M) {
    __shared__ float Ws[FEAT2 * FEAT3];   // 20 KB
    __shared__ float As[64][FEAT2 + 1];   // +1 pad: kill 64-way bank conflict
    int t = threadIdx.x;
    int n0 = blockIdx.x * 64;
    for (int i = t; i < FEAT2 * FEAT3; i += 64) Ws[i] = W[i];
    for (int i = t; i < 64 * FEAT2 / 4; i += 64) {
        int row = i >> 5;           // 32 float4 per row
        int kq = i & 31;
        int gr = n0 + row;
        float4 v = make_float4(0.f, 0.f, 0.f, 0.f);
        if (gr < M) v = *(const float4*)(A + (long)gr * FEAT2 + kq * 4);
        *(float4*)(&As[row][kq * 4]) = v;
    }
    __syncthreads();
    float acc[FEAT3];
    #pragma unroll
    for (int j = 0; j < FEAT3; j++) acc[j] = 0.f;
    for (int k = 0; k < FEAT2; k++) {
        float a = As[t][k];
        #pragma unroll
        for (int j = 0; j < FEAT3; j++) acc[j] += a * Ws[k * FEAT3 + j];  // Ws: LDS broadcast
    }
    int node = n0 + t;
    if (node < M) {
        float di = dinv[node];
        #pragma unroll
        for (int j = 0; j < FEAT3; j++) C[(long)node * FEAT3 + j] = acc[j] * di;
    }
}

// ---- Aggregation layer 2 + bias + log_softmax: 1 wave per node --------------
__launch_bounds__(64)
__global__ void agg2_lsm_kernel(const float* __restrict__ h2s, const int* __restrict__ col,
                                const int* __restrict__ off, const float* __restrict__ dinv,
                                const float* __restrict__ b2, float* __restrict__ out) {
    int i = blockIdx.x;
    int t = threadIdx.x;   // 64 threads, lanes 0..39 active for features
    int o0 = off[i], o1 = off[i + 1];
    bool act = t < FEAT3;
    float acc = 0.f;
    for (int j = o0; j < o1; ++j) {
        int s = col[j];     // uniform within block -> scalar load
        if (act) acc += h2s[(long)s * FEAT3 + t];
    }
    float di = dinv[i];
    float v = act ? (acc + h2s[(long)i * FEAT3 + t]) * di + b2[t] : -INFINITY;
    float m = v;
    #pragma unroll
    for (int o = 32; o >= 1; o >>= 1) m = fmaxf(m, __shfl_xor(m, o));
    float e = act ? expf(v - m) : 0.f;
    float ssum = e;
    #pragma unroll
    for (int o = 32; o >= 1; o >>= 1) ssum += __shfl_xor(ssum, o);
    if (act) out[(long)i * FEAT3 + t] = v - m - logf(ssum);
}

// ---------------------------------------------------------------------------
extern "C" void kernel_launch(void* const* d_in, const int* in_sizes, int n_in,
                              void* d_out, int out_size, void* d_ws, size_t ws_size,
                              hipStream_t stream) {
    const float* x  = (const float*)d_in[0];
    const int*   ei = (const int*)d_in[1];
    const float* W1 = (const float*)d_in[2];
    const float* b1 = (const float*)d_in[3];
    const float* W2 = (const float*)d_in[4];
    const float* b2 = (const float*)d_in[5];
    float* out = (float*)d_out;

    const int  N = in_sizes[0] / FEAT1;       // 50000
    const long E = in_sizes[1] / 2;           // 1600000

    // workspace carve-up (256B aligned)
    char* ws = (char*)d_ws;
    size_t off = 0;
    auto alloc = [&](size_t bytes) -> void* {
        off = (off + 255) & ~(size_t)255;
        void* p = ws + off;
        off += bytes;
        return p;
    };
    int*   counts  = (int*)alloc((size_t)N * 4);
    int*   offsets = (int*)alloc((size_t)(N + 1) * 4);
    int*   cursor  = (int*)alloc((size_t)N * 4);
    float* dinv    = (float*)alloc((size_t)N * 4);
    int*   col     = (int*)alloc((size_t)E * 4);
    float* h1s     = (float*)alloc((size_t)N * FEAT2 * 4);
    float* a1      = (float*)alloc((size_t)N * FEAT2 * 4);
    float* h2s     = (float*)alloc((size_t)N * FEAT3 * 4);
    int*   bsums   = (int*)alloc(256 * 4);
    int*   flagp   = (int*)alloc(4);

    const int nb = (N + 255) / 256;           // 196 scan blocks

    detect_i64_kernel<<<1, 256, 0, stream>>>(ei, flagp);
    hipMemsetAsync(counts, 0, (size_t)N * 4, stream);
    hist_kernel<<<2048, 256, 0, stream>>>(ei, flagp, counts, E);
    scan_block_kernel<<<nb, 256, 0, stream>>>(counts, offsets, bsums, N);
    scan_block_kernel<<<1, 256, 0, stream>>>(bsums, bsums, nullptr, nb);
    scan_finalize_kernel<<<nb, 256, 0, stream>>>(counts, offsets, bsums, cursor, dinv, N, (int)E);
    fill_kernel<<<2048, 256, 0, stream>>>(ei, flagp, cursor, col, E);

    gemm1_kernel<<<(N + 63) / 64, 256, 0, stream>>>(x, W1, dinv, h1s, N);
    agg1_kernel<<<N, 128, 0, stream>>>(h1s, col, offsets, dinv, b1, a1);
    gemm2_kernel<<<(N + 63) / 64, 64, 0, stream>>>(a1, W2, dinv, h2s, N);
    agg2_lsm_kernel<<<N, 64, 0, stream>>>(h2s, col, offsets, dinv, b2, out);
}

// Round 2
// 676.596 us; speedup vs baseline: 1.0296x; 1.0296x over previous
//
#include <hip/hip_runtime.h>
#include <hip/hip_bf16.h>
#include <math.h>

// ---------------------------------------------------------------------------
// GCN 2-layer. A_hat = D^-1/2 (A+I) D^-1/2 factored as: scale GEMM rows by
// dinv (epilogue), gather-sum neighbors, scale by dinv[dst], add self term.
// CSR built on device per call (int atomics only; no float atomics).
// Round 2 changes:
//   - fill_kernel: XCD-range-partitioned scatter (blockIdx&7 == dst range) so
//     col-line writes stay in one XCD's L2 -> kill the 101MB write traffic.
//   - h1s / h2s stored bf16 -> halve the gather traffic in agg1/agg2.
//   - gemm1 As tile padded (+1) to remove 8-way LDS write bank conflict.
// ---------------------------------------------------------------------------

#define FEAT1 512
#define FEAT2 128
#define FEAT3 40

__device__ __forceinline__ unsigned short f2bf(float f) {
    union { float f; unsigned u; } c; c.f = f;
    unsigned r = c.u + 0x7fff + ((c.u >> 16) & 1);   // round-nearest-even
    return (unsigned short)(r >> 16);
}
__device__ __forceinline__ float bf2f(unsigned v16) {  // low 16 bits used
    union { unsigned u; float f; } c; c.u = v16 << 16;
    return c.f;
}

// ---- edge_index may be int32 (JAX default) or int64. -----------------------
__global__ void detect_i64_kernel(const int* __restrict__ ei, int* flagp) {
    __shared__ int any;
    if (threadIdx.x == 0) any = 0;
    __syncthreads();
    int v = ei[2 * threadIdx.x + 1];
    if (v != 0) any = 1;
    __syncthreads();
    if (threadIdx.x == 0) *flagp = (any == 0) ? 1 : 0;   // 1 => int64 layout
}

__device__ __forceinline__ int load_src(const int* ei, long e, long E, int f64) {
    return f64 ? ei[2 * e] : ei[e];
}
__device__ __forceinline__ int load_dst(const int* ei, long e, long E, int f64) {
    return f64 ? ei[2 * E + 2 * e] : ei[E + e];
}

// ---- CSR build --------------------------------------------------------------
__global__ void hist_kernel(const int* __restrict__ ei, const int* __restrict__ flagp,
                            int* __restrict__ counts, long E) {
    int f64 = *flagp;
    long i = (long)blockIdx.x * blockDim.x + threadIdx.x;
    long stride = (long)gridDim.x * blockDim.x;
    for (; i < E; i += stride) {
        int dst = load_dst(ei, i, E, f64);
        atomicAdd(&counts[dst], 1);
    }
}

__global__ void scan_block_kernel(const int* __restrict__ in, int* __restrict__ excl,
                                  int* __restrict__ bsums, int N) {
    __shared__ int s[256];
    int t = threadIdx.x;
    int gid = blockIdx.x * 256 + t;
    int v = (gid < N) ? in[gid] : 0;
    s[t] = v;
    __syncthreads();
    #pragma unroll
    for (int d = 1; d < 256; d <<= 1) {
        int tv = (t >= d) ? s[t - d] : 0;
        __syncthreads();
        s[t] += tv;
        __syncthreads();
    }
    if (gid < N) excl[gid] = s[t] - v;
    if (t == 255 && bsums) bsums[blockIdx.x] = s[255];
}

__global__ void scan_finalize_kernel(const int* __restrict__ counts, int* __restrict__ off,
                                     const int* __restrict__ bsums, int* __restrict__ cursor,
                                     float* __restrict__ dinv, int N, int E) {
    int gid = blockIdx.x * 256 + threadIdx.x;
    if (gid < N) {
        int o = off[gid] + bsums[blockIdx.x];
        off[gid] = o;
        cursor[gid] = o;
        dinv[gid] = 1.0f / sqrtf((float)(counts[gid] + 1));
    }
    if (gid == 0) off[N] = E;
}

// XCD-range-partitioned scatter: block b handles only dst in range (b&7).
// Workgroup dispatch round-robins XCDs, so range (b&7) writes are confined to
// one XCD's L2 (800KB window << 4MB) -> full lines written back once.
__global__ void fill_kernel(const int* __restrict__ ei, const int* __restrict__ flagp,
                            int* __restrict__ cursor, int* __restrict__ col,
                            long E, int N) {
    int f64 = *flagp;
    int r = blockIdx.x & 7;
    int lo = (int)((long)N * r >> 3);
    int hi = (int)((long)N * (r + 1) >> 3);
    long i = (long)(blockIdx.x >> 3) * blockDim.x + threadIdx.x;
    long stride = (long)(gridDim.x >> 3) * blockDim.x;
    for (; i < E; i += stride) {
        int dst = load_dst(ei, i, E, f64);
        if (dst >= lo && dst < hi) {
            int src = load_src(ei, i, E, f64);
            int pos = atomicAdd(&cursor[dst], 1);
            col[pos] = src;
        }
    }
}

// ---- GEMM1: [M,512]@[512,128] f32, epilogue *dinv[row], store bf16 ----------
__launch_bounds__(256)
__global__ void gemm1_kernel(const float* __restrict__ A, const float* __restrict__ B,
                             const float* __restrict__ dinv, unsigned short* __restrict__ C,
                             int M) {
    __shared__ float As[32][65];    // [k][m], +1 pad kills 8-way write conflict
    __shared__ float Bs[32][128];   // [k][n]
    int t = threadIdx.x;
    int m0 = blockIdx.x * 64;
    int ty = t >> 4, tx = t & 15;
    float acc[4][8];
    #pragma unroll
    for (int r = 0; r < 4; r++)
        #pragma unroll
        for (int c = 0; c < 8; c++) acc[r][c] = 0.f;

    for (int k0 = 0; k0 < FEAT1; k0 += 32) {
        #pragma unroll
        for (int i = 0; i < 2; i++) {
            int id = t + i * 256;
            int row = id >> 3;
            int kq = id & 7;
            int grow = m0 + row;
            float4 v = make_float4(0.f, 0.f, 0.f, 0.f);
            if (grow < M) v = *(const float4*)(A + (long)grow * FEAT1 + k0 + kq * 4);
            As[kq * 4 + 0][row] = v.x;
            As[kq * 4 + 1][row] = v.y;
            As[kq * 4 + 2][row] = v.z;
            As[kq * 4 + 3][row] = v.w;
        }
        #pragma unroll
        for (int i = 0; i < 4; i++) {
            int id = t + i * 256;
            int kr = id >> 5;
            int nq = id & 31;
            *(float4*)(&Bs[kr][nq * 4]) = *(const float4*)(B + (long)(k0 + kr) * FEAT2 + nq * 4);
        }
        __syncthreads();
        #pragma unroll
        for (int kk = 0; kk < 32; ++kk) {
            float ra[4], rb[8];
            #pragma unroll
            for (int r = 0; r < 4; r++) ra[r] = As[kk][ty * 4 + r];
            #pragma unroll
            for (int c = 0; c < 8; c++) rb[c] = Bs[kk][tx * 8 + c];
            #pragma unroll
            for (int r = 0; r < 4; r++)
                #pragma unroll
                for (int c = 0; c < 8; c++) acc[r][c] += ra[r] * rb[c];
        }
        __syncthreads();
    }
    #pragma unroll
    for (int r = 0; r < 4; r++) {
        int grow = m0 + ty * 4 + r;
        if (grow >= M) continue;
        float di = dinv[grow];
        unsigned p[4];
        #pragma unroll
        for (int c = 0; c < 4; c++) {
            p[c] = (unsigned)f2bf(acc[r][2 * c] * di) |
                   ((unsigned)f2bf(acc[r][2 * c + 1] * di) << 16);
        }
        // 8 bf16 = 16B per thread, contiguous within row
        *(uint4*)((unsigned*)(C + (long)grow * FEAT2 + tx * 8)) =
            make_uint4(p[0], p[1], p[2], p[3]);
    }
}

// ---- Aggregation 1: block(256)=4 waves per node; bf16x2 gathers -------------
__launch_bounds__(256)
__global__ void agg1_kernel(const unsigned short* __restrict__ h1s,
                            const int* __restrict__ col, const int* __restrict__ off,
                            const float* __restrict__ dinv, const float* __restrict__ b1,
                            float* __restrict__ a1) {
    int i = blockIdx.x;
    int t = threadIdx.x;
    int w = t >> 6, l = t & 63;       // wave id, lane id; lane handles feats 2l,2l+1
    __shared__ int sc[256];
    __shared__ float2 red[4][64];
    int o0 = off[i], o1 = off[i + 1];
    float ax = 0.f, ay = 0.f;
    for (int base = o0; base < o1; base += 256) {
        int cnt = min(256, o1 - base);
        __syncthreads();
        if (t < cnt) sc[t] = col[base + t];
        __syncthreads();
        for (int j = w; j < cnt; j += 4) {
            unsigned pv = *(const unsigned*)(h1s + (long)sc[j] * FEAT2 + 2 * l);
            ax += bf2f(pv & 0xffffu);
            ay += bf2f(pv >> 16);
        }
    }
    red[w][l] = make_float2(ax, ay);
    __syncthreads();
    if (w == 0) {
        float2 s = red[0][l];
        #pragma unroll
        for (int q = 1; q < 4; q++) { s.x += red[q][l].x; s.y += red[q][l].y; }
        unsigned pv = *(const unsigned*)(h1s + (long)i * FEAT2 + 2 * l);  // self
        s.x += bf2f(pv & 0xffffu);
        s.y += bf2f(pv >> 16);
        float di = dinv[i];
        float2 b = *(const float2*)(b1 + 2 * l);
        float vx = s.x * di + b.x;
        float vy = s.y * di + b.y;
        vx = vx > 0.f ? vx : 0.f;
        vy = vy > 0.f ? vy : 0.f;
        *(float2*)(a1 + (long)i * FEAT2 + 2 * l) = make_float2(vx, vy);
    }
}

// ---- GEMM2: [M,128]@[128,40] node-per-thread, *dinv, store bf16 -------------
__launch_bounds__(64)
__global__ void gemm2_kernel(const float* __restrict__ A, const float* __restrict__ W,
                             const float* __restrict__ dinv, unsigned short* __restrict__ C,
                             int M) {
    __shared__ float Ws[FEAT2 * FEAT3];   // 20 KB
    __shared__ float As[64][FEAT2 + 1];
    int t = threadIdx.x;
    int n0 = blockIdx.x * 64;
    for (int i = t; i < FEAT2 * FEAT3; i += 64) Ws[i] = W[i];
    for (int i = t; i < 64 * FEAT2 / 4; i += 64) {
        int row = i >> 5;
        int kq = i & 31;
        int gr = n0 + row;
        float4 v = make_float4(0.f, 0.f, 0.f, 0.f);
        if (gr < M) v = *(const float4*)(A + (long)gr * FEAT2 + kq * 4);
        *(float4*)(&As[row][kq * 4]) = v;
    }
    __syncthreads();
    float acc[FEAT3];
    #pragma unroll
    for (int j = 0; j < FEAT3; j++) acc[j] = 0.f;
    for (int k = 0; k < FEAT2; k++) {
        float a = As[t][k];
        #pragma unroll
        for (int j = 0; j < FEAT3; j++) acc[j] += a * Ws[k * FEAT3 + j];
    }
    int node = n0 + t;
    if (node < M) {
        float di = dinv[node];
        unsigned* cp = (unsigned*)(C + (long)node * FEAT3);
        #pragma unroll
        for (int j = 0; j < FEAT3 / 2; j++) {
            cp[j] = (unsigned)f2bf(acc[2 * j] * di) |
                    ((unsigned)f2bf(acc[2 * j + 1] * di) << 16);
        }
    }
}

// ---- Aggregation 2 + bias + log_softmax: 1 wave per node, bf16x2 gathers ----
__launch_bounds__(64)
__global__ void agg2_lsm_kernel(const unsigned short* __restrict__ h2s,
                                const int* __restrict__ col, const int* __restrict__ off,
                                const float* __restrict__ dinv, const float* __restrict__ b2,
                                float* __restrict__ out) {
    int i = blockIdx.x;
    int t = threadIdx.x;          // lanes 0..19 handle feature pairs
    bool act = t < FEAT3 / 2;
    int o0 = off[i], o1 = off[i + 1];
    float ax = 0.f, ay = 0.f;
    for (int j = o0; j < o1; ++j) {
        int s = col[j];            // uniform -> scalar load
        if (act) {
            unsigned pv = *(const unsigned*)(h2s + (long)s * FEAT3 + 2 * t);
            ax += bf2f(pv & 0xffffu);
            ay += bf2f(pv >> 16);
        }
    }
    float vx = -INFINITY, vy = -INFINITY;
    if (act) {
        unsigned pv = *(const unsigned*)(h2s + (long)i * FEAT3 + 2 * t);  // self
        float di = dinv[i];
        float2 b = *(const float2*)(b2 + 2 * t);
        vx = (ax + bf2f(pv & 0xffffu)) * di + b.x;
        vy = (ay + bf2f(pv >> 16)) * di + b.y;
    }
    float m = fmaxf(vx, vy);
    #pragma unroll
    for (int o = 32; o >= 1; o >>= 1) m = fmaxf(m, __shfl_xor(m, o));
    float e = act ? (expf(vx - m) + expf(vy - m)) : 0.f;
    #pragma unroll
    for (int o = 32; o >= 1; o >>= 1) e += __shfl_xor(e, o);
    float ls = logf(e);
    if (act) {
        *(float2*)(out + (long)i * FEAT3 + 2 * t) = make_float2(vx - m - ls, vy - m - ls);
    }
}

// ---------------------------------------------------------------------------
extern "C" void kernel_launch(void* const* d_in, const int* in_sizes, int n_in,
                              void* d_out, int out_size, void* d_ws, size_t ws_size,
                              hipStream_t stream) {
    const float* x  = (const float*)d_in[0];
    const int*   ei = (const int*)d_in[1];
    const float* W1 = (const float*)d_in[2];
    const float* b1 = (const float*)d_in[3];
    const float* W2 = (const float*)d_in[4];
    const float* b2 = (const float*)d_in[5];
    float* out = (float*)d_out;

    const int  N = in_sizes[0] / FEAT1;       // 50000
    const long E = in_sizes[1] / 2;           // 1600000

    char* ws = (char*)d_ws;
    size_t off = 0;
    auto alloc = [&](size_t bytes) -> void* {
        off = (off + 255) & ~(size_t)255;
        void* p = ws + off;
        off += bytes;
        return p;
    };
    int*   counts  = (int*)alloc((size_t)N * 4);
    int*   offsets = (int*)alloc((size_t)(N + 1) * 4);
    int*   cursor  = (int*)alloc((size_t)N * 4);
    float* dinv    = (float*)alloc((size_t)N * 4);
    int*   col     = (int*)alloc((size_t)E * 4);
    unsigned short* h1s = (unsigned short*)alloc((size_t)N * FEAT2 * 2);
    float* a1      = (float*)alloc((size_t)N * FEAT2 * 4);
    unsigned short* h2s = (unsigned short*)alloc((size_t)N * FEAT3 * 2);
    int*   bsums   = (int*)alloc(256 * 4);
    int*   flagp   = (int*)alloc(4);

    const int nb = (N + 255) / 256;

    detect_i64_kernel<<<1, 256, 0, stream>>>(ei, flagp);
    hipMemsetAsync(counts, 0, (size_t)N * 4, stream);
    hist_kernel<<<2048, 256, 0, stream>>>(ei, flagp, counts, E);
    scan_block_kernel<<<nb, 256, 0, stream>>>(counts, offsets, bsums, N);
    scan_block_kernel<<<1, 256, 0, stream>>>(bsums, bsums, nullptr, nb);
    scan_finalize_kernel<<<nb, 256, 0, stream>>>(counts, offsets, bsums, cursor, dinv, N, (int)E);
    fill_kernel<<<2048, 256, 0, stream>>>(ei, flagp, cursor, col, E, N);

    gemm1_kernel<<<(N + 63) / 64, 256, 0, stream>>>(x, W1, dinv, h1s, N);
    agg1_kernel<<<N, 256, 0, stream>>>(h1s, col, offsets, dinv, b1, a1);
    gemm2_kernel<<<(N + 63) / 64, 64, 0, stream>>>(a1, W2, dinv, h2s, N);
    agg2_lsm_kernel<<<N, 64, 0, stream>>>(h2s, col, offsets, dinv, b2, out);
}

// Round 3
// 588.147 us; speedup vs baseline: 1.1845x; 1.1504x over previous
//
#include <hip/hip_runtime.h>
#include <hip/hip_bf16.h>
#include <math.h>

// ---------------------------------------------------------------------------
// GCN 2-layer. A_hat = D^-1/2 (A+I) D^-1/2 factored: scale GEMM rows by dinv
// (epilogue), gather-sum neighbors, scale by dinv[dst], add self term.
// Round 3: gemm1 -> bf16 MFMA (16x16x32). A converted f32->bf16 in-kernel and
// staged to LDS in fragment order (conflict-free ds_read_b128); W1 pre-
// transposed to bf16 Bt[128][512] so B-fragments are direct 16B global loads.
// ---------------------------------------------------------------------------

#define FEAT1 512
#define FEAT2 128
#define FEAT3 40

typedef __attribute__((ext_vector_type(8))) short bf16x8;
typedef __attribute__((ext_vector_type(4))) float f32x4;

__device__ __forceinline__ unsigned short f2bf(float f) {
    union { float f; unsigned u; } c; c.f = f;
    unsigned r = c.u + 0x7fff + ((c.u >> 16) & 1);   // round-nearest-even
    return (unsigned short)(r >> 16);
}
__device__ __forceinline__ float bf2f(unsigned v16) {
    union { unsigned u; float f; } c; c.u = v16 << 16;
    return c.f;
}

// ---- edge_index may be int32 (JAX default) or int64. -----------------------
__global__ void detect_i64_kernel(const int* __restrict__ ei, int* flagp) {
    __shared__ int any;
    if (threadIdx.x == 0) any = 0;
    __syncthreads();
    int v = ei[2 * threadIdx.x + 1];
    if (v != 0) any = 1;
    __syncthreads();
    if (threadIdx.x == 0) *flagp = (any == 0) ? 1 : 0;   // 1 => int64 layout
}

__device__ __forceinline__ int load_src(const int* ei, long e, long E, int f64) {
    return f64 ? ei[2 * e] : ei[e];
}
__device__ __forceinline__ int load_dst(const int* ei, long e, long E, int f64) {
    return f64 ? ei[2 * E + 2 * e] : ei[E + e];
}

// ---- CSR build --------------------------------------------------------------
__global__ void hist_kernel(const int* __restrict__ ei, const int* __restrict__ flagp,
                            int* __restrict__ counts, long E) {
    int f64 = *flagp;
    long i = (long)blockIdx.x * blockDim.x + threadIdx.x;
    long stride = (long)gridDim.x * blockDim.x;
    for (; i < E; i += stride) {
        int dst = load_dst(ei, i, E, f64);
        atomicAdd(&counts[dst], 1);
    }
}

__global__ void scan_block_kernel(const int* __restrict__ in, int* __restrict__ excl,
                                  int* __restrict__ bsums, int N) {
    __shared__ int s[256];
    int t = threadIdx.x;
    int gid = blockIdx.x * 256 + t;
    int v = (gid < N) ? in[gid] : 0;
    s[t] = v;
    __syncthreads();
    #pragma unroll
    for (int d = 1; d < 256; d <<= 1) {
        int tv = (t >= d) ? s[t - d] : 0;
        __syncthreads();
        s[t] += tv;
        __syncthreads();
    }
    if (gid < N) excl[gid] = s[t] - v;
    if (t == 255 && bsums) bsums[blockIdx.x] = s[255];
}

__global__ void scan_finalize_kernel(const int* __restrict__ counts, int* __restrict__ off,
                                     const int* __restrict__ bsums, int* __restrict__ cursor,
                                     float* __restrict__ dinv, int N, int E) {
    int gid = blockIdx.x * 256 + threadIdx.x;
    if (gid < N) {
        int o = off[gid] + bsums[blockIdx.x];
        off[gid] = o;
        cursor[gid] = o;
        dinv[gid] = 1.0f / sqrtf((float)(counts[gid] + 1));
    }
    if (gid == 0) off[N] = E;
}

// XCD-range-partitioned scatter (blockIdx&7 == dst range) keeps col-line
// writes in one XCD's L2 -> full-line writebacks.
__global__ void fill_kernel(const int* __restrict__ ei, const int* __restrict__ flagp,
                            int* __restrict__ cursor, int* __restrict__ col,
                            long E, int N) {
    int f64 = *flagp;
    int r = blockIdx.x & 7;
    int lo = (int)((long)N * r >> 3);
    int hi = (int)((long)N * (r + 1) >> 3);
    long i = (long)(blockIdx.x >> 3) * blockDim.x + threadIdx.x;
    long stride = (long)(gridDim.x >> 3) * blockDim.x;
    for (; i < E; i += stride) {
        int dst = load_dst(ei, i, E, f64);
        if (dst >= lo && dst < hi) {
            int src = load_src(ei, i, E, f64);
            int pos = atomicAdd(&cursor[dst], 1);
            col[pos] = src;
        }
    }
}

// ---- W1 [512,128] f32 -> Bt [128][512] bf16 (n-major, k-contiguous) --------
__global__ void w1bt_kernel(const float* __restrict__ W1, unsigned short* __restrict__ Bt) {
    int n = blockIdx.x;
    for (int k = threadIdx.x; k < FEAT1; k += blockDim.x)
        Bt[(long)n * FEAT1 + k] = f2bf(W1[(long)k * FEAT2 + n]);
}

// ---- GEMM1 (MFMA): [M,512]f32 x Bt[128][512]bf16 -> h1s bf16, *dinv[row] ---
// BM=64, BN=128, BK=32; 4 waves 2x2, each wave 32x64 (2x4 tiles of 16x16x32).
__launch_bounds__(256)
__global__ void gemm1_mfma_kernel(const float* __restrict__ A,
                                  const unsigned short* __restrict__ Bt,
                                  const float* __restrict__ dinv,
                                  unsigned short* __restrict__ C, int M) {
    __shared__ uint4 Asm[256];          // 64 rows x 32 k bf16, fragment order, 4 KB
    int t = threadIdx.x;
    int m0 = blockIdx.x * 64;
    int w = t >> 6, lane = t & 63;
    int wr = w >> 1, wc = w & 1;        // wave quadrant: rows 32*wr, cols 64*wc
    int quad = lane >> 4, r15 = lane & 15;

    f32x4 acc[2][4];
    #pragma unroll
    for (int mt = 0; mt < 2; mt++)
        #pragma unroll
        for (int nt = 0; nt < 4; nt++) acc[mt][nt] = (f32x4){0.f, 0.f, 0.f, 0.f};

    for (int k0 = 0; k0 < FEAT1; k0 += 32) {
        __syncthreads();
        // stage A tile: 64x32 f32 -> bf16 fragment order
        #pragma unroll
        for (int i = 0; i < 2; i++) {
            int id = t + i * 256;
            int row = id >> 3, q = id & 7;        // q: float4 index in the 32-k row
            int grow = m0 + row;
            float4 v = make_float4(0.f, 0.f, 0.f, 0.f);
            if (grow < M) v = *(const float4*)(A + (long)grow * FEAT1 + k0 + q * 4);
            uint2 p;
            p.x = (unsigned)f2bf(v.x) | ((unsigned)f2bf(v.y) << 16);
            p.y = (unsigned)f2bf(v.z) | ((unsigned)f2bf(v.w) << 16);
            // fragment position: mtile=row>>4, lane'=(row&15)+(q>>1)*16, half=q&1
            ((uint2*)Asm)[(row >> 4) * 128 + (((row & 15) + ((q >> 1) << 4)) << 1) + (q & 1)] = p;
        }
        __syncthreads();

        bf16x8 af[2];
        #pragma unroll
        for (int mt = 0; mt < 2; mt++)
            af[mt] = ((const bf16x8*)Asm)[(wr * 2 + mt) * 64 + lane];

        #pragma unroll
        for (int nt = 0; nt < 4; nt++) {
            // B fragment: B[k][n], n=r15, k=quad*8+j -> k-contiguous 16B in Bt
            bf16x8 bf = *(const bf16x8*)(Bt + (long)(wc * 64 + nt * 16 + r15) * FEAT1 + k0 + quad * 8);
            acc[0][nt] = __builtin_amdgcn_mfma_f32_16x16x32_bf16(af[0], bf, acc[0][nt], 0, 0, 0);
            acc[1][nt] = __builtin_amdgcn_mfma_f32_16x16x32_bf16(af[1], bf, acc[1][nt], 0, 0, 0);
        }
    }

    // epilogue: C/D layout col=lane&15, row=quad*4+reg
    #pragma unroll
    for (int mt = 0; mt < 2; mt++) {
        int rb = m0 + wr * 32 + mt * 16 + quad * 4;
        #pragma unroll
        for (int reg = 0; reg < 4; reg++) {
            int row = rb + reg;
            if (row >= M) continue;
            float di = dinv[row];
            #pragma unroll
            for (int nt = 0; nt < 4; nt++) {
                C[(long)row * FEAT2 + wc * 64 + nt * 16 + r15] = f2bf(acc[mt][nt][reg] * di);
            }
        }
    }
}

// ---- Aggregation 1: block(256)=4 waves per node; bf16x2 gathers -------------
__launch_bounds__(256)
__global__ void agg1_kernel(const unsigned short* __restrict__ h1s,
                            const int* __restrict__ col, const int* __restrict__ off,
                            const float* __restrict__ dinv, const float* __restrict__ b1,
                            float* __restrict__ a1) {
    int i = blockIdx.x;
    int t = threadIdx.x;
    int w = t >> 6, l = t & 63;
    __shared__ int sc[256];
    __shared__ float2 red[4][64];
    int o0 = off[i], o1 = off[i + 1];
    float ax = 0.f, ay = 0.f;
    for (int base = o0; base < o1; base += 256) {
        int cnt = min(256, o1 - base);
        __syncthreads();
        if (t < cnt) sc[t] = col[base + t];
        __syncthreads();
        for (int j = w; j < cnt; j += 4) {
            unsigned pv = *(const unsigned*)(h1s + (long)sc[j] * FEAT2 + 2 * l);
            ax += bf2f(pv & 0xffffu);
            ay += bf2f(pv >> 16);
        }
    }
    red[w][l] = make_float2(ax, ay);
    __syncthreads();
    if (w == 0) {
        float2 s = red[0][l];
        #pragma unroll
        for (int q = 1; q < 4; q++) { s.x += red[q][l].x; s.y += red[q][l].y; }
        unsigned pv = *(const unsigned*)(h1s + (long)i * FEAT2 + 2 * l);  // self
        s.x += bf2f(pv & 0xffffu);
        s.y += bf2f(pv >> 16);
        float di = dinv[i];
        float2 b = *(const float2*)(b1 + 2 * l);
        float vx = s.x * di + b.x;
        float vy = s.y * di + b.y;
        vx = vx > 0.f ? vx : 0.f;
        vy = vy > 0.f ? vy : 0.f;
        *(float2*)(a1 + (long)i * FEAT2 + 2 * l) = make_float2(vx, vy);
    }
}

// ---- GEMM2: [M,128]@[128,40] node-per-thread, *dinv, store bf16 -------------
__launch_bounds__(64)
__global__ void gemm2_kernel(const float* __restrict__ A, const float* __restrict__ W,
                             const float* __restrict__ dinv, unsigned short* __restrict__ C,
                             int M) {
    __shared__ float Ws[FEAT2 * FEAT3];
    __shared__ float As[64][FEAT2 + 1];
    int t = threadIdx.x;
    int n0 = blockIdx.x * 64;
    for (int i = t; i < FEAT2 * FEAT3; i += 64) Ws[i] = W[i];
    for (int i = t; i < 64 * FEAT2 / 4; i += 64) {
        int row = i >> 5;
        int kq = i & 31;
        int gr = n0 + row;
        float4 v = make_float4(0.f, 0.f, 0.f, 0.f);
        if (gr < M) v = *(const float4*)(A + (long)gr * FEAT2 + kq * 4);
        *(float4*)(&As[row][kq * 4]) = v;
    }
    __syncthreads();
    float acc[FEAT3];
    #pragma unroll
    for (int j = 0; j < FEAT3; j++) acc[j] = 0.f;
    for (int k = 0; k < FEAT2; k++) {
        float a = As[t][k];
        #pragma unroll
        for (int j = 0; j < FEAT3; j++) acc[j] += a * Ws[k * FEAT3 + j];
    }
    int node = n0 + t;
    if (node < M) {
        float di = dinv[node];
        unsigned* cp = (unsigned*)(C + (long)node * FEAT3);
        #pragma unroll
        for (int j = 0; j < FEAT3 / 2; j++) {
            cp[j] = (unsigned)f2bf(acc[2 * j] * di) |
                    ((unsigned)f2bf(acc[2 * j + 1] * di) << 16);
        }
    }
}

// ---- Aggregation 2 + bias + log_softmax: 1 wave per node --------------------
__launch_bounds__(64)
__global__ void agg2_lsm_kernel(const unsigned short* __restrict__ h2s,
                                const int* __restrict__ col, const int* __restrict__ off,
                                const float* __restrict__ dinv, const float* __restrict__ b2,
                                float* __restrict__ out) {
    int i = blockIdx.x;
    int t = threadIdx.x;
    bool act = t < FEAT3 / 2;
    int o0 = off[i], o1 = off[i + 1];
    float ax = 0.f, ay = 0.f;
    for (int j = o0; j < o1; ++j) {
        int s = col[j];
        if (act) {
            unsigned pv = *(const unsigned*)(h2s + (long)s * FEAT3 + 2 * t);
            ax += bf2f(pv & 0xffffu);
            ay += bf2f(pv >> 16);
        }
    }
    float vx = -INFINITY, vy = -INFINITY;
    if (act) {
        unsigned pv = *(const unsigned*)(h2s + (long)i * FEAT3 + 2 * t);
        float di = dinv[i];
        float2 b = *(const float2*)(b2 + 2 * t);
        vx = (ax + bf2f(pv & 0xffffu)) * di + b.x;
        vy = (ay + bf2f(pv >> 16)) * di + b.y;
    }
    float m = fmaxf(vx, vy);
    #pragma unroll
    for (int o = 32; o >= 1; o >>= 1) m = fmaxf(m, __shfl_xor(m, o));
    float e = act ? (expf(vx - m) + expf(vy - m)) : 0.f;
    #pragma unroll
    for (int o = 32; o >= 1; o >>= 1) e += __shfl_xor(e, o);
    float ls = logf(e);
    if (act) {
        *(float2*)(out + (long)i * FEAT3 + 2 * t) = make_float2(vx - m - ls, vy - m - ls);
    }
}

// ---------------------------------------------------------------------------
extern "C" void kernel_launch(void* const* d_in, const int* in_sizes, int n_in,
                              void* d_out, int out_size, void* d_ws, size_t ws_size,
                              hipStream_t stream) {
    const float* x  = (const float*)d_in[0];
    const int*   ei = (const int*)d_in[1];
    const float* W1 = (const float*)d_in[2];
    const float* b1 = (const float*)d_in[3];
    const float* W2 = (const float*)d_in[4];
    const float* b2 = (const float*)d_in[5];
    float* out = (float*)d_out;

    const int  N = in_sizes[0] / FEAT1;       // 50000
    const long E = in_sizes[1] / 2;           // 1600000

    char* ws = (char*)d_ws;
    size_t off = 0;
    auto alloc = [&](size_t bytes) -> void* {
        off = (off + 255) & ~(size_t)255;
        void* p = ws + off;
        off += bytes;
        return p;
    };
    int*   counts  = (int*)alloc((size_t)N * 4);
    int*   offsets = (int*)alloc((size_t)(N + 1) * 4);
    int*   cursor  = (int*)alloc((size_t)N * 4);
    float* dinv    = (float*)alloc((size_t)N * 4);
    int*   col     = (int*)alloc((size_t)E * 4);
    unsigned short* h1s = (unsigned short*)alloc((size_t)N * FEAT2 * 2);
    float* a1      = (float*)alloc((size_t)N * FEAT2 * 4);
    unsigned short* h2s = (unsigned short*)alloc((size_t)N * FEAT3 * 2);
    unsigned short* Bt  = (unsigned short*)alloc((size_t)FEAT2 * FEAT1 * 2);
    int*   bsums   = (int*)alloc(256 * 4);
    int*   flagp   = (int*)alloc(4);

    const int nb = (N + 255) / 256;

    detect_i64_kernel<<<1, 256, 0, stream>>>(ei, flagp);
    hipMemsetAsync(counts, 0, (size_t)N * 4, stream);
    hist_kernel<<<2048, 256, 0, stream>>>(ei, flagp, counts, E);
    scan_block_kernel<<<nb, 256, 0, stream>>>(counts, offsets, bsums, N);
    scan_block_kernel<<<1, 256, 0, stream>>>(bsums, bsums, nullptr, nb);
    scan_finalize_kernel<<<nb, 256, 0, stream>>>(counts, offsets, bsums, cursor, dinv, N, (int)E);
    fill_kernel<<<2048, 256, 0, stream>>>(ei, flagp, cursor, col, E, N);

    w1bt_kernel<<<FEAT2, 256, 0, stream>>>(W1, Bt);
    gemm1_mfma_kernel<<<(N + 63) / 64, 256, 0, stream>>>(x, Bt, dinv, h1s, N);
    agg1_kernel<<<N, 256, 0, stream>>>(h1s, col, offsets, dinv, b1, a1);
    gemm2_kernel<<<(N + 63) / 64, 64, 0, stream>>>(a1, W2, dinv, h2s, N);
    agg2_lsm_kernel<<<N, 64, 0, stream>>>(h2s, col, offsets, dinv, b2, out);
}

// Round 4
// 497.441 us; speedup vs baseline: 1.4004x; 1.1823x over previous
//
#include <hip/hip_runtime.h>
#include <hip/hip_bf16.h>
#include <math.h>

// ---------------------------------------------------------------------------
// GCN 2-layer. A_hat = D^-1/2 (A+I) D^-1/2 factored: scale GEMM rows by dinv
// (epilogue), gather-sum neighbors, scale by dinv[dst], add self term.
// Round 4: agg1/agg2 -> wave-per-node (no LDS, no syncthreads). Col indices
// loaded 64-wide coalesced once, broadcast via __shfl; gather loop 4-way
// unrolled for MLP. Avg degree 32 -> one col load per node.
// ---------------------------------------------------------------------------

#define FEAT1 512
#define FEAT2 128
#define FEAT3 40

typedef __attribute__((ext_vector_type(8))) short bf16x8;
typedef __attribute__((ext_vector_type(4))) float f32x4;

__device__ __forceinline__ unsigned short f2bf(float f) {
    union { float f; unsigned u; } c; c.f = f;
    unsigned r = c.u + 0x7fff + ((c.u >> 16) & 1);   // round-nearest-even
    return (unsigned short)(r >> 16);
}
__device__ __forceinline__ float bf2f(unsigned v16) {
    union { unsigned u; float f; } c; c.u = v16 << 16;
    return c.f;
}

// ---- edge_index may be int32 (JAX default) or int64. -----------------------
__global__ void detect_i64_kernel(const int* __restrict__ ei, int* flagp) {
    __shared__ int any;
    if (threadIdx.x == 0) any = 0;
    __syncthreads();
    int v = ei[2 * threadIdx.x + 1];
    if (v != 0) any = 1;
    __syncthreads();
    if (threadIdx.x == 0) *flagp = (any == 0) ? 1 : 0;   // 1 => int64 layout
}

__device__ __forceinline__ int load_src(const int* ei, long e, long E, int f64) {
    return f64 ? ei[2 * e] : ei[e];
}
__device__ __forceinline__ int load_dst(const int* ei, long e, long E, int f64) {
    return f64 ? ei[2 * E + 2 * e] : ei[E + e];
}

// ---- CSR build --------------------------------------------------------------
__global__ void hist_kernel(const int* __restrict__ ei, const int* __restrict__ flagp,
                            int* __restrict__ counts, long E) {
    int f64 = *flagp;
    long i = (long)blockIdx.x * blockDim.x + threadIdx.x;
    long stride = (long)gridDim.x * blockDim.x;
    for (; i < E; i += stride) {
        int dst = load_dst(ei, i, E, f64);
        atomicAdd(&counts[dst], 1);
    }
}

__global__ void scan_block_kernel(const int* __restrict__ in, int* __restrict__ excl,
                                  int* __restrict__ bsums, int N) {
    __shared__ int s[256];
    int t = threadIdx.x;
    int gid = blockIdx.x * 256 + t;
    int v = (gid < N) ? in[gid] : 0;
    s[t] = v;
    __syncthreads();
    #pragma unroll
    for (int d = 1; d < 256; d <<= 1) {
        int tv = (t >= d) ? s[t - d] : 0;
        __syncthreads();
        s[t] += tv;
        __syncthreads();
    }
    if (gid < N) excl[gid] = s[t] - v;
    if (t == 255 && bsums) bsums[blockIdx.x] = s[255];
}

__global__ void scan_finalize_kernel(const int* __restrict__ counts, int* __restrict__ off,
                                     const int* __restrict__ bsums, int* __restrict__ cursor,
                                     float* __restrict__ dinv, int N, int E) {
    int gid = blockIdx.x * 256 + threadIdx.x;
    if (gid < N) {
        int o = off[gid] + bsums[blockIdx.x];
        off[gid] = o;
        cursor[gid] = o;
        dinv[gid] = 1.0f / sqrtf((float)(counts[gid] + 1));
    }
    if (gid == 0) off[N] = E;
}

// XCD-range-partitioned scatter (blockIdx&7 == dst range) keeps col-line
// writes in one XCD's L2 -> full-line writebacks.
__global__ void fill_kernel(const int* __restrict__ ei, const int* __restrict__ flagp,
                            int* __restrict__ cursor, int* __restrict__ col,
                            long E, int N) {
    int f64 = *flagp;
    int r = blockIdx.x & 7;
    int lo = (int)((long)N * r >> 3);
    int hi = (int)((long)N * (r + 1) >> 3);
    long i = (long)(blockIdx.x >> 3) * blockDim.x + threadIdx.x;
    long stride = (long)(gridDim.x >> 3) * blockDim.x;
    for (; i < E; i += stride) {
        int dst = load_dst(ei, i, E, f64);
        if (dst >= lo && dst < hi) {
            int src = load_src(ei, i, E, f64);
            int pos = atomicAdd(&cursor[dst], 1);
            col[pos] = src;
        }
    }
}

// ---- W1 [512,128] f32 -> Bt [128][512] bf16 (n-major, k-contiguous) --------
__global__ void w1bt_kernel(const float* __restrict__ W1, unsigned short* __restrict__ Bt) {
    int n = blockIdx.x;
    for (int k = threadIdx.x; k < FEAT1; k += blockDim.x)
        Bt[(long)n * FEAT1 + k] = f2bf(W1[(long)k * FEAT2 + n]);
}

// ---- GEMM1 (MFMA): [M,512]f32 x Bt[128][512]bf16 -> h1s bf16, *dinv[row] ---
__launch_bounds__(256)
__global__ void gemm1_mfma_kernel(const float* __restrict__ A,
                                  const unsigned short* __restrict__ Bt,
                                  const float* __restrict__ dinv,
                                  unsigned short* __restrict__ C, int M) {
    __shared__ uint4 Asm[256];          // 64 rows x 32 k bf16, fragment order, 4 KB
    int t = threadIdx.x;
    int m0 = blockIdx.x * 64;
    int w = t >> 6, lane = t & 63;
    int wr = w >> 1, wc = w & 1;
    int quad = lane >> 4, r15 = lane & 15;

    f32x4 acc[2][4];
    #pragma unroll
    for (int mt = 0; mt < 2; mt++)
        #pragma unroll
        for (int nt = 0; nt < 4; nt++) acc[mt][nt] = (f32x4){0.f, 0.f, 0.f, 0.f};

    for (int k0 = 0; k0 < FEAT1; k0 += 32) {
        __syncthreads();
        #pragma unroll
        for (int i = 0; i < 2; i++) {
            int id = t + i * 256;
            int row = id >> 3, q = id & 7;
            int grow = m0 + row;
            float4 v = make_float4(0.f, 0.f, 0.f, 0.f);
            if (grow < M) v = *(const float4*)(A + (long)grow * FEAT1 + k0 + q * 4);
            uint2 p;
            p.x = (unsigned)f2bf(v.x) | ((unsigned)f2bf(v.y) << 16);
            p.y = (unsigned)f2bf(v.z) | ((unsigned)f2bf(v.w) << 16);
            ((uint2*)Asm)[(row >> 4) * 128 + (((row & 15) + ((q >> 1) << 4)) << 1) + (q & 1)] = p;
        }
        __syncthreads();

        bf16x8 af[2];
        #pragma unroll
        for (int mt = 0; mt < 2; mt++)
            af[mt] = ((const bf16x8*)Asm)[(wr * 2 + mt) * 64 + lane];

        #pragma unroll
        for (int nt = 0; nt < 4; nt++) {
            bf16x8 bf = *(const bf16x8*)(Bt + (long)(wc * 64 + nt * 16 + r15) * FEAT1 + k0 + quad * 8);
            acc[0][nt] = __builtin_amdgcn_mfma_f32_16x16x32_bf16(af[0], bf, acc[0][nt], 0, 0, 0);
            acc[1][nt] = __builtin_amdgcn_mfma_f32_16x16x32_bf16(af[1], bf, acc[1][nt], 0, 0, 0);
        }
    }

    #pragma unroll
    for (int mt = 0; mt < 2; mt++) {
        int rb = m0 + wr * 32 + mt * 16 + quad * 4;
        #pragma unroll
        for (int reg = 0; reg < 4; reg++) {
            int row = rb + reg;
            if (row >= M) continue;
            float di = dinv[row];
            #pragma unroll
            for (int nt = 0; nt < 4; nt++) {
                C[(long)row * FEAT2 + wc * 64 + nt * 16 + r15] = f2bf(acc[mt][nt][reg] * di);
            }
        }
    }
}

// ---- Aggregation 1: wave-per-node; shfl-broadcast col, 4-way unrolled -------
__launch_bounds__(256)
__global__ void agg1_kernel(const unsigned short* __restrict__ h1s,
                            const int* __restrict__ col, const int* __restrict__ off,
                            const float* __restrict__ dinv, const float* __restrict__ b1,
                            float* __restrict__ a1, int N) {
    int node = blockIdx.x * 4 + (threadIdx.x >> 6);
    if (node >= N) return;
    int l = threadIdx.x & 63;            // lane handles feats 2l, 2l+1
    int o0 = off[node], o1 = off[node + 1];
    float ax = 0.f, ay = 0.f;
    for (int base = o0; base < o1; base += 64) {
        int cnt = min(64, o1 - base);
        int myc = (l < cnt) ? col[base + l] : 0;   // one coalesced 64-wide load
        int e = 0;
        for (; e + 4 <= cnt; e += 4) {
            int s0 = __shfl(myc, e + 0);
            int s1 = __shfl(myc, e + 1);
            int s2 = __shfl(myc, e + 2);
            int s3 = __shfl(myc, e + 3);
            unsigned p0 = *(const unsigned*)(h1s + (long)s0 * FEAT2 + 2 * l);
            unsigned p1 = *(const unsigned*)(h1s + (long)s1 * FEAT2 + 2 * l);
            unsigned p2 = *(const unsigned*)(h1s + (long)s2 * FEAT2 + 2 * l);
            unsigned p3 = *(const unsigned*)(h1s + (long)s3 * FEAT2 + 2 * l);
            ax += bf2f(p0 & 0xffffu) + bf2f(p1 & 0xffffu) +
                  bf2f(p2 & 0xffffu) + bf2f(p3 & 0xffffu);
            ay += bf2f(p0 >> 16) + bf2f(p1 >> 16) + bf2f(p2 >> 16) + bf2f(p3 >> 16);
        }
        for (; e < cnt; ++e) {
            int s = __shfl(myc, e);
            unsigned p = *(const unsigned*)(h1s + (long)s * FEAT2 + 2 * l);
            ax += bf2f(p & 0xffffu);
            ay += bf2f(p >> 16);
        }
    }
    unsigned pv = *(const unsigned*)(h1s + (long)node * FEAT2 + 2 * l);  // self
    ax += bf2f(pv & 0xffffu);
    ay += bf2f(pv >> 16);
    float di = dinv[node];
    float2 b = *(const float2*)(b1 + 2 * l);
    float vx = ax * di + b.x;
    float vy = ay * di + b.y;
    vx = vx > 0.f ? vx : 0.f;
    vy = vy > 0.f ? vy : 0.f;
    *(float2*)(a1 + (long)node * FEAT2 + 2 * l) = make_float2(vx, vy);
}

// ---- GEMM2: [M,128]@[128,40] node-per-thread, *dinv, store bf16 -------------
__launch_bounds__(64)
__global__ void gemm2_kernel(const float* __restrict__ A, const float* __restrict__ W,
                             const float* __restrict__ dinv, unsigned short* __restrict__ C,
                             int M) {
    __shared__ float Ws[FEAT2 * FEAT3];
    __shared__ float As[64][FEAT2 + 1];
    int t = threadIdx.x;
    int n0 = blockIdx.x * 64;
    for (int i = t; i < FEAT2 * FEAT3; i += 64) Ws[i] = W[i];
    for (int i = t; i < 64 * FEAT2 / 4; i += 64) {
        int row = i >> 5;
        int kq = i & 31;
        int gr = n0 + row;
        float4 v = make_float4(0.f, 0.f, 0.f, 0.f);
        if (gr < M) v = *(const float4*)(A + (long)gr * FEAT2 + kq * 4);
        *(float4*)(&As[row][kq * 4]) = v;
    }
    __syncthreads();
    float acc[FEAT3];
    #pragma unroll
    for (int j = 0; j < FEAT3; j++) acc[j] = 0.f;
    for (int k = 0; k < FEAT2; k++) {
        float a = As[t][k];
        #pragma unroll
        for (int j = 0; j < FEAT3; j++) acc[j] += a * Ws[k * FEAT3 + j];
    }
    int node = n0 + t;
    if (node < M) {
        float di = dinv[node];
        unsigned* cp = (unsigned*)(C + (long)node * FEAT3);
        #pragma unroll
        for (int j = 0; j < FEAT3 / 2; j++) {
            cp[j] = (unsigned)f2bf(acc[2 * j] * di) |
                    ((unsigned)f2bf(acc[2 * j + 1] * di) << 16);
        }
    }
}

// ---- Aggregation 2 + log_softmax: wave-per-node, shfl col, 4-way unroll -----
__launch_bounds__(256)
__global__ void agg2_lsm_kernel(const unsigned short* __restrict__ h2s,
                                const int* __restrict__ col, const int* __restrict__ off,
                                const float* __restrict__ dinv, const float* __restrict__ b2,
                                float* __restrict__ out, int N) {
    int node = blockIdx.x * 4 + (threadIdx.x >> 6);
    if (node >= N) return;
    int l = threadIdx.x & 63;
    bool act = l < FEAT3 / 2;             // lanes 0..19 hold feature pairs
    int o0 = off[node], o1 = off[node + 1];
    float ax = 0.f, ay = 0.f;
    for (int base = o0; base < o1; base += 64) {
        int cnt = min(64, o1 - base);
        int myc = (l < cnt) ? col[base + l] : 0;
        int e = 0;
        for (; e + 4 <= cnt; e += 4) {
            int s0 = __shfl(myc, e + 0);
            int s1 = __shfl(myc, e + 1);
            int s2 = __shfl(myc, e + 2);
            int s3 = __shfl(myc, e + 3);
            if (act) {
                unsigned p0 = *(const unsigned*)(h2s + (long)s0 * FEAT3 + 2 * l);
                unsigned p1 = *(const unsigned*)(h2s + (long)s1 * FEAT3 + 2 * l);
                unsigned p2 = *(const unsigned*)(h2s + (long)s2 * FEAT3 + 2 * l);
                unsigned p3 = *(const unsigned*)(h2s + (long)s3 * FEAT3 + 2 * l);
                ax += bf2f(p0 & 0xffffu) + bf2f(p1 & 0xffffu) +
                      bf2f(p2 & 0xffffu) + bf2f(p3 & 0xffffu);
                ay += bf2f(p0 >> 16) + bf2f(p1 >> 16) + bf2f(p2 >> 16) + bf2f(p3 >> 16);
            }
        }
        for (; e < cnt; ++e) {
            int s = __shfl(myc, e);
            if (act) {
                unsigned p = *(const unsigned*)(h2s + (long)s * FEAT3 + 2 * l);
                ax += bf2f(p & 0xffffu);
                ay += bf2f(p >> 16);
            }
        }
    }
    float vx = -INFINITY, vy = -INFINITY;
    if (act) {
        unsigned pv = *(const unsigned*)(h2s + (long)node * FEAT3 + 2 * l);  // self
        float di = dinv[node];
        float2 b = *(const float2*)(b2 + 2 * l);
        vx = (ax + bf2f(pv & 0xffffu)) * di + b.x;
        vy = (ay + bf2f(pv >> 16)) * di + b.y;
    }
    float m = fmaxf(vx, vy);
    #pragma unroll
    for (int o = 32; o >= 1; o >>= 1) m = fmaxf(m, __shfl_xor(m, o));
    float e = act ? (expf(vx - m) + expf(vy - m)) : 0.f;
    #pragma unroll
    for (int o = 32; o >= 1; o >>= 1) e += __shfl_xor(e, o);
    float ls = logf(e);
    if (act) {
        *(float2*)(out + (long)node * FEAT3 + 2 * l) = make_float2(vx - m - ls, vy - m - ls);
    }
}

// ---------------------------------------------------------------------------
extern "C" void kernel_launch(void* const* d_in, const int* in_sizes, int n_in,
                              void* d_out, int out_size, void* d_ws, size_t ws_size,
                              hipStream_t stream) {
    const float* x  = (const float*)d_in[0];
    const int*   ei = (const int*)d_in[1];
    const float* W1 = (const float*)d_in[2];
    const float* b1 = (const float*)d_in[3];
    const float* W2 = (const float*)d_in[4];
    const float* b2 = (const float*)d_in[5];
    float* out = (float*)d_out;

    const int  N = in_sizes[0] / FEAT1;       // 50000
    const long E = in_sizes[1] / 2;           // 1600000

    char* ws = (char*)d_ws;
    size_t off = 0;
    auto alloc = [&](size_t bytes) -> void* {
        off = (off + 255) & ~(size_t)255;
        void* p = ws + off;
        off += bytes;
        return p;
    };
    int*   counts  = (int*)alloc((size_t)N * 4);
    int*   offsets = (int*)alloc((size_t)(N + 1) * 4);
    int*   cursor  = (int*)alloc((size_t)N * 4);
    float* dinv    = (float*)alloc((size_t)N * 4);
    int*   col     = (int*)alloc((size_t)E * 4);
    unsigned short* h1s = (unsigned short*)alloc((size_t)N * FEAT2 * 2);
    float* a1      = (float*)alloc((size_t)N * FEAT2 * 4);
    unsigned short* h2s = (unsigned short*)alloc((size_t)N * FEAT3 * 2);
    unsigned short* Bt  = (unsigned short*)alloc((size_t)FEAT2 * FEAT1 * 2);
    int*   bsums   = (int*)alloc(256 * 4);
    int*   flagp   = (int*)alloc(4);

    const int nb = (N + 255) / 256;

    detect_i64_kernel<<<1, 256, 0, stream>>>(ei, flagp);
    hipMemsetAsync(counts, 0, (size_t)N * 4, stream);
    hist_kernel<<<2048, 256, 0, stream>>>(ei, flagp, counts, E);
    scan_block_kernel<<<nb, 256, 0, stream>>>(counts, offsets, bsums, N);
    scan_block_kernel<<<1, 256, 0, stream>>>(bsums, bsums, nullptr, nb);
    scan_finalize_kernel<<<nb, 256, 0, stream>>>(counts, offsets, bsums, cursor, dinv, N, (int)E);
    fill_kernel<<<2048, 256, 0, stream>>>(ei, flagp, cursor, col, E, N);

    w1bt_kernel<<<FEAT2, 256, 0, stream>>>(W1, Bt);
    gemm1_mfma_kernel<<<(N + 63) / 64, 256, 0, stream>>>(x, Bt, dinv, h1s, N);
    agg1_kernel<<<(N + 3) / 4, 256, 0, stream>>>(h1s, col, offsets, dinv, b1, a1, N);
    gemm2_kernel<<<(N + 63) / 64, 64, 0, stream>>>(a1, W2, dinv, h2s, N);
    agg2_lsm_kernel<<<(N + 3) / 4, 256, 0, stream>>>(h2s, col, offsets, dinv, b2, out, N);
}